// Round 3
// baseline (364.498 us; speedup 1.0000x reference)
//
#include <hip/hip_runtime.h>
#include <math.h>

#define N_STATES 32
#define N_TYPES 128
#define N_GENES 8192
#define N_SAMPLES 8192
#define LOG2PI_F 1.8378770664093453f

typedef float f32x4 __attribute__((ext_vector_type(4)));

// ---------------- Kernel 1: per-(state,gene) tables ----------------
__global__ __launch_bounds__(256) void precompute_kernel(
    const float* __restrict__ cp, const float* __restrict__ Zmu,
    const float* __restrict__ Zs, float* __restrict__ muT,
    float* __restrict__ invT, float* __restrict__ lcT) {
  __shared__ float s_cp[2][N_TYPES];
  __shared__ float s_cp2[2][N_TYPES];
  const int st0 = blockIdx.y * 2;
  const int g0 = (blockIdx.x * 256 + threadIdx.x) * 4;

  for (int idx = threadIdx.x; idx < 2 * N_TYPES; idx += 256) {
    int s = idx >> 7, t = idx & (N_TYPES - 1);
    float c = cp[(st0 + s) * N_TYPES + t];
    s_cp[s][t] = c;
    s_cp2[s][t] = c * c;
  }
  __syncthreads();

  float mu[2][4], s13[2][4], s2[2][4];
#pragma unroll
  for (int s = 0; s < 2; ++s)
#pragma unroll
    for (int j = 0; j < 4; ++j) { mu[s][j] = 0.f; s13[s][j] = 0.f; s2[s][j] = 0.f; }

  for (int t = 0; t < N_TYPES; ++t) {
    f32x4 zm = *(const f32x4*)(Zmu + t * N_GENES + g0);
    f32x4 zs = *(const f32x4*)(Zs + t * N_GENES + g0);
#pragma unroll
    for (int s = 0; s < 2; ++s) {
      float c = s_cp[s][t], c2 = s_cp2[s][t];
#pragma unroll
      for (int j = 0; j < 4; ++j) {
        mu[s][j]  = fmaf(c, zm[j], mu[s][j]);
        s2[s][j]  = fmaf(c, zs[j], s2[s][j]);
        s13[s][j] = fmaf(c2, zs[j] * (1.f - zs[j]), s13[s][j]);
      }
    }
  }

#pragma unroll
  for (int s = 0; s < 2; ++s) {
    f32x4 mv, iv, lv;
#pragma unroll
    for (int j = 0; j < 4; ++j) {
      float sigma = s13[s][j] + s2[s][j] * s2[s][j];
      mv[j] = mu[s][j];
      iv[j] = 1.0f / sigma;
      lv[j] = logf(sigma) + 0.5f * LOG2PI_F;
    }
    int o = (st0 + s) * N_GENES + g0;
    *(f32x4*)(muT + o)  = mv;
    *(f32x4*)(invT + o) = iv;
    *(f32x4*)(lcT + o)  = lv;
  }
}

// ---------------- Kernel 2: main elementwise + partial reduction ----------------
// Each thread: 8 groups x 16 consecutive elements. 16 | 8192 -> one row/state
// per group. All 16 f32x4 loads issued before compute (deep MLP). Output is
// shifted +1 (out[0] = scalar sum); repack in registers so the 3 interior
// stores are aligned f32x4, with 4 scalar boundary stores.
__global__ __launch_bounds__(256) void main_kernel(
    const float* __restrict__ X, const int* __restrict__ day,
    const float* __restrict__ muT, const float* __restrict__ invT,
    const float* __restrict__ lcT, float* __restrict__ out,
    float* __restrict__ partial) {
  const int tid = blockIdx.x * 256 + threadIdx.x;
  const int NT = 2048 * 256;                       // 524288 threads

  float acc = 0.f;
#pragma unroll 1
  for (int grp = 0; grp < 8; ++grp) {
    const int gidx = tid + grp * NT;               // 0 .. 4194303
    const int b = gidx << 4;                       // base element index
    const int row = b >> 13;                       // / N_GENES
    const int st = day[row] - 1;
    const int gb = b & (N_GENES - 1);

    const f32x4* Xp = (const f32x4*)(X + b);
    const f32x4* Mp = (const f32x4*)(muT + st * N_GENES + gb);
    const f32x4* Ip = (const f32x4*)(invT + st * N_GENES + gb);
    const f32x4* Lp = (const f32x4*)(lcT + st * N_GENES + gb);

    f32x4 x0 = Xp[0], x1 = Xp[1], x2 = Xp[2], x3 = Xp[3];
    f32x4 m0 = Mp[0], m1 = Mp[1], m2 = Mp[2], m3 = Mp[3];
    f32x4 i0 = Ip[0], i1 = Ip[1], i2 = Ip[2], i3 = Ip[3];
    f32x4 l0 = Lp[0], l1 = Lp[1], l2 = Lp[2], l3 = Lp[3];

    f32x4 p0, p1, p2, p3;
#pragma unroll
    for (int j = 0; j < 4; ++j) {
      float z;
      z = (x0[j] - m0[j]) * i0[j]; p0[j] = fmaf(-0.5f * z, z, -l0[j]);
      z = (x1[j] - m1[j]) * i1[j]; p1[j] = fmaf(-0.5f * z, z, -l1[j]);
      z = (x2[j] - m2[j]) * i2[j]; p2[j] = fmaf(-0.5f * z, z, -l2[j]);
      z = (x3[j] - m3[j]) * i3[j]; p3[j] = fmaf(-0.5f * z, z, -l3[j]);
    }

    // out[b+1 .. b+16] = p[0..15]
    f32x4 v0, v1, v2;
    v0[0] = p0[3]; v0[1] = p1[0]; v0[2] = p1[1]; v0[3] = p1[2];
    v1[0] = p1[3]; v1[1] = p2[0]; v1[2] = p2[1]; v1[3] = p2[2];
    v2[0] = p2[3]; v2[1] = p3[0]; v2[2] = p3[1]; v2[3] = p3[2];
    float* ob = out + b;
    __builtin_nontemporal_store(v0, (f32x4*)(ob + 4));
    __builtin_nontemporal_store(v1, (f32x4*)(ob + 8));
    __builtin_nontemporal_store(v2, (f32x4*)(ob + 12));
    __builtin_nontemporal_store(p0[0], ob + 1);
    __builtin_nontemporal_store(p0[1], ob + 2);
    __builtin_nontemporal_store(p0[2], ob + 3);
    __builtin_nontemporal_store(p3[3], ob + 16);

    f32x4 ps = (p0 + p1) + (p2 + p3);
    acc += (ps[0] + ps[1]) + (ps[2] + ps[3]);
  }

#pragma unroll
  for (int off = 32; off; off >>= 1) acc += __shfl_down(acc, off, 64);
  __shared__ float s_w[4];
  int lane = threadIdx.x & 63, w = threadIdx.x >> 6;
  if (lane == 0) s_w[w] = acc;
  __syncthreads();
  if (threadIdx.x == 0)
    partial[blockIdx.x] = (s_w[0] + s_w[1]) + (s_w[2] + s_w[3]);
}

// ---------------- Kernel 3: final reduction (deterministic, double) ----------------
__global__ __launch_bounds__(256) void reduce_kernel(
    const float* __restrict__ partial, int n, float* __restrict__ out0) {
  double acc = 0.0;
  for (int i = threadIdx.x; i < n; i += 256) acc += (double)partial[i];
#pragma unroll
  for (int off = 32; off; off >>= 1) acc += __shfl_down(acc, off, 64);
  __shared__ double s_w[4];
  int lane = threadIdx.x & 63, w = threadIdx.x >> 6;
  if (lane == 0) s_w[w] = acc;
  __syncthreads();
  if (threadIdx.x == 0) out0[0] = (float)((s_w[0] + s_w[1]) + (s_w[2] + s_w[3]));
}

extern "C" void kernel_launch(void* const* d_in, const int* in_sizes, int n_in,
                              void* d_out, int out_size, void* d_ws, size_t ws_size,
                              hipStream_t stream) {
  const float* cp  = (const float*)d_in[0];   // (32,128)
  const float* Zmu = (const float*)d_in[1];   // (128,8192)
  const float* Zs  = (const float*)d_in[2];   // (128,8192)
  const float* X   = (const float*)d_in[3];   // (8192,8192)
  const int*   day = (const int*)d_in[4];     // (8192,)
  float* out = (float*)d_out;                 // [0]=sum, [1..]=logp flat
  float* ws  = (float*)d_ws;

  const int TBL = N_STATES * N_GENES;
  float* muT     = ws;
  float* invT    = ws + TBL;
  float* lcT     = ws + 2 * TBL;
  float* partial = ws + 3 * TBL;

  dim3 g1(N_GENES / 1024, N_STATES / 2);      // 8 x 16 = 128 blocks
  precompute_kernel<<<g1, 256, 0, stream>>>(cp, Zmu, Zs, muT, invT, lcT);

  const int NBLK = 2048;
  main_kernel<<<NBLK, 256, 0, stream>>>(X, day, muT, invT, lcT, out, partial);
  reduce_kernel<<<1, 256, 0, stream>>>(partial, NBLK, out);
}

// Round 4
// 184.568 us; speedup vs baseline: 1.9749x; 1.9749x over previous
//
#include <hip/hip_runtime.h>
#include <math.h>

#define N_STATES 32
#define N_TYPES 128
#define N_GENES 8192
#define N_SAMPLES 8192
#define LOG2PI_F 1.8378770664093453f

typedef float f32x4 __attribute__((ext_vector_type(4)));

// ---------------- Kernel 1: per-(state,gene) tables ----------------
// mu[st,g] = sum_t cp*Zmu ; sigma = sum_t cp^2*zs*(1-zs) + (sum_t cp*zs)^2
// store mu and inv = 1/sigma  (log computed in main kernel; VALU is idle there)
__global__ __launch_bounds__(256) void precompute_kernel(
    const float* __restrict__ cp, const float* __restrict__ Zmu,
    const float* __restrict__ Zs, float* __restrict__ muT,
    float* __restrict__ invT) {
  __shared__ float s_cp[2][N_TYPES];
  __shared__ float s_cp2[2][N_TYPES];
  const int st0 = blockIdx.y * 2;
  const int g0 = (blockIdx.x * 256 + threadIdx.x) * 4;

  for (int idx = threadIdx.x; idx < 2 * N_TYPES; idx += 256) {
    int s = idx >> 7, t = idx & (N_TYPES - 1);
    float c = cp[(st0 + s) * N_TYPES + t];
    s_cp[s][t] = c;
    s_cp2[s][t] = c * c;
  }
  __syncthreads();

  float mu[2][4], s13[2][4], s2[2][4];
#pragma unroll
  for (int s = 0; s < 2; ++s)
#pragma unroll
    for (int j = 0; j < 4; ++j) { mu[s][j] = 0.f; s13[s][j] = 0.f; s2[s][j] = 0.f; }

  for (int t = 0; t < N_TYPES; ++t) {
    f32x4 zm = *(const f32x4*)(Zmu + t * N_GENES + g0);
    f32x4 zs = *(const f32x4*)(Zs + t * N_GENES + g0);
#pragma unroll
    for (int s = 0; s < 2; ++s) {
      float c = s_cp[s][t], c2 = s_cp2[s][t];
#pragma unroll
      for (int j = 0; j < 4; ++j) {
        mu[s][j]  = fmaf(c, zm[j], mu[s][j]);
        s2[s][j]  = fmaf(c, zs[j], s2[s][j]);
        s13[s][j] = fmaf(c2, zs[j] * (1.f - zs[j]), s13[s][j]);
      }
    }
  }

#pragma unroll
  for (int s = 0; s < 2; ++s) {
    f32x4 mv, iv;
#pragma unroll
    for (int j = 0; j < 4; ++j) {
      float sigma = s13[s][j] + s2[s][j] * s2[s][j];
      mv[j] = mu[s][j];
      iv[j] = 1.0f / sigma;
    }
    int o = (st0 + s) * N_GENES + g0;
    *(f32x4*)(muT + o)  = mv;
    *(f32x4*)(invT + o) = iv;
  }
}

// ---------------- Kernel 2: main elementwise + partial reduction ----------------
// Block b owns rows 4b..4b+3. day[row] is wave-uniform (s_load, hoisted) so
// table bases are SGPRs -> no per-iteration dependent gather chain. Inner 8
// chunks fully unrolled -> 24 independent f32x4 loads in flight per wave.
// Output is logp shifted +1 (out[0] = scalar sum): 4 coalesced dword stores.
__global__ __launch_bounds__(256) void main_kernel(
    const float* __restrict__ X, const int* __restrict__ day,
    const float* __restrict__ muT, const float* __restrict__ invT,
    float* __restrict__ out, float* __restrict__ partial) {
  const int row0 = blockIdx.x * 4;
  float acc = 0.f;

#pragma unroll 1
  for (int r = 0; r < 4; ++r) {
    const int row = row0 + r;
    const int st = day[row] - 1;                       // uniform scalar
    const f32x4* Xr = (const f32x4*)(X + (size_t)row * N_GENES);
    const f32x4* Mr = (const f32x4*)(muT + st * N_GENES);
    const f32x4* Ir = (const f32x4*)(invT + st * N_GENES);
    float* outr = out + (size_t)row * N_GENES + 1;     // +1 shift

#pragma unroll
    for (int it = 0; it < 8; ++it) {
      const int c = it * 256 + threadIdx.x;            // chunk within row
      f32x4 x  = Xr[c];
      f32x4 m  = Mr[c];
      f32x4 iv = Ir[c];

      f32x4 p;
#pragma unroll
      for (int j = 0; j < 4; ++j) {
        float z = (x[j] - m[j]) * iv[j];
        // logp = -0.5 z^2 - log(sigma) - 0.5 log(2pi);  log(sigma) = -log(inv)
        p[j] = fmaf(-0.5f * z, z, __logf(iv[j]) - 0.5f * LOG2PI_F);
      }

      float* ob = outr + 4 * c;
      ob[0] = p[0];
      ob[1] = p[1];
      ob[2] = p[2];
      ob[3] = p[3];

      acc += (p[0] + p[1]) + (p[2] + p[3]);
    }
  }

#pragma unroll
  for (int off = 32; off; off >>= 1) acc += __shfl_down(acc, off, 64);
  __shared__ float s_w[4];
  int lane = threadIdx.x & 63, w = threadIdx.x >> 6;
  if (lane == 0) s_w[w] = acc;
  __syncthreads();
  if (threadIdx.x == 0)
    partial[blockIdx.x] = (s_w[0] + s_w[1]) + (s_w[2] + s_w[3]);
}

// ---------------- Kernel 3: final reduction (deterministic, double) ----------------
__global__ __launch_bounds__(256) void reduce_kernel(
    const float* __restrict__ partial, int n, float* __restrict__ out0) {
  double acc = 0.0;
  for (int i = threadIdx.x; i < n; i += 256) acc += (double)partial[i];
#pragma unroll
  for (int off = 32; off; off >>= 1) acc += __shfl_down(acc, off, 64);
  __shared__ double s_w[4];
  int lane = threadIdx.x & 63, w = threadIdx.x >> 6;
  if (lane == 0) s_w[w] = acc;
  __syncthreads();
  if (threadIdx.x == 0) out0[0] = (float)((s_w[0] + s_w[1]) + (s_w[2] + s_w[3]));
}

extern "C" void kernel_launch(void* const* d_in, const int* in_sizes, int n_in,
                              void* d_out, int out_size, void* d_ws, size_t ws_size,
                              hipStream_t stream) {
  const float* cp  = (const float*)d_in[0];   // (32,128)
  const float* Zmu = (const float*)d_in[1];   // (128,8192)
  const float* Zs  = (const float*)d_in[2];   // (128,8192)
  const float* X   = (const float*)d_in[3];   // (8192,8192)
  const int*   day = (const int*)d_in[4];     // (8192,)
  float* out = (float*)d_out;                 // [0]=sum, [1..]=logp flat
  float* ws  = (float*)d_ws;

  const int TBL = N_STATES * N_GENES;
  float* muT     = ws;
  float* invT    = ws + TBL;
  float* partial = ws + 2 * TBL;

  dim3 g1(N_GENES / 1024, N_STATES / 2);      // 8 x 16 = 128 blocks
  precompute_kernel<<<g1, 256, 0, stream>>>(cp, Zmu, Zs, muT, invT);

  const int NBLK = N_SAMPLES / 4;             // 2048 blocks, 4 rows each
  main_kernel<<<NBLK, 256, 0, stream>>>(X, day, muT, invT, out, partial);
  reduce_kernel<<<1, 256, 0, stream>>>(partial, NBLK, out);
}

// Round 5
// 135.089 us; speedup vs baseline: 2.6982x; 1.3663x over previous
//
#include <hip/hip_runtime.h>
#include <math.h>

#define N_STATES 32
#define N_TYPES 128
#define N_GENES 8192
#define N_SAMPLES 8192
#define LOG2PI_F 1.8378770664093453f

typedef float f32x4 __attribute__((ext_vector_type(4)));

// ---------------- Kernel 1: per-(state,gene) tables ----------------
// mu[st,g] = sum_t cp*Zmu ; sigma = sum_t cp^2*zs*(1-zs) + (sum_t cp*zs)^2
// 1 state per block, 1024 genes per block (4/thread), t-loop unrolled x4.
__global__ __launch_bounds__(256) void precompute_kernel(
    const float* __restrict__ cp, const float* __restrict__ Zmu,
    const float* __restrict__ Zs, float* __restrict__ muT,
    float* __restrict__ invT) {
  __shared__ float s_cp[N_TYPES], s_cp2[N_TYPES];
  const int st = blockIdx.y;
  const int g0 = blockIdx.x * 1024 + threadIdx.x * 4;

  if (threadIdx.x < N_TYPES) {
    float c = cp[st * N_TYPES + threadIdx.x];
    s_cp[threadIdx.x] = c;
    s_cp2[threadIdx.x] = c * c;
  }
  __syncthreads();

  float mu[4] = {0,0,0,0}, s13[4] = {0,0,0,0}, s2[4] = {0,0,0,0};
#pragma unroll 1
  for (int t = 0; t < N_TYPES; t += 4) {
    f32x4 zm[4], zs[4];
#pragma unroll
    for (int u = 0; u < 4; ++u) {
      zm[u] = *(const f32x4*)(Zmu + (size_t)(t + u) * N_GENES + g0);
      zs[u] = *(const f32x4*)(Zs  + (size_t)(t + u) * N_GENES + g0);
    }
#pragma unroll
    for (int u = 0; u < 4; ++u) {
      float c = s_cp[t + u], c2 = s_cp2[t + u];
#pragma unroll
      for (int j = 0; j < 4; ++j) {
        mu[j]  = fmaf(c, zm[u][j], mu[j]);
        s2[j]  = fmaf(c, zs[u][j], s2[j]);
        s13[j] = fmaf(c2, zs[u][j] * (1.f - zs[u][j]), s13[j]);
      }
    }
  }

  f32x4 mv, iv;
#pragma unroll
  for (int j = 0; j < 4; ++j) {
    float sigma = s13[j] + s2[j] * s2[j];
    mv[j] = mu[j];
    iv[j] = 1.0f / sigma;
  }
  int o = st * N_GENES + g0;
  *(f32x4*)(muT + o)  = mv;
  *(f32x4*)(invT + o) = iv;
}

// ---------------- Kernel 2: main elementwise + partial reduction ----------------
// Block b owns rows 4b..4b+3 (day -> SGPR table base). Per row: batch-load all
// 8 chunks of X/mu/inv into 24 f32x4 registers, sched_barrier pins the batch
// ahead of compute -> 24 loads in flight per wave (latency-parallelism fix).
__global__ __launch_bounds__(256) void main_kernel(
    const float* __restrict__ X, const int* __restrict__ day,
    const float* __restrict__ muT, const float* __restrict__ invT,
    float* __restrict__ out, float* __restrict__ partial) {
  const int row0 = blockIdx.x * 4;
  const int tid = threadIdx.x;
  float acc = 0.f;

#pragma unroll 1
  for (int r = 0; r < 4; ++r) {
    const int row = row0 + r;
    const int st = day[row] - 1;                        // wave-uniform
    const f32x4* Xr = (const f32x4*)(X + (size_t)row * N_GENES) + tid;
    const f32x4* Mr = (const f32x4*)(muT + (size_t)st * N_GENES) + tid;
    const f32x4* Ir = (const f32x4*)(invT + (size_t)st * N_GENES) + tid;

    f32x4 x[8], m[8], iv[8];
#pragma unroll
    for (int it = 0; it < 8; ++it) x[it]  = Xr[it * 256];
#pragma unroll
    for (int it = 0; it < 8; ++it) m[it]  = Mr[it * 256];
#pragma unroll
    for (int it = 0; it < 8; ++it) iv[it] = Ir[it * 256];
    __builtin_amdgcn_sched_barrier(0);                  // pin: no sinking loads

    float* ob = out + (size_t)row * N_GENES + 1 + tid * 4;  // +1 shift
#pragma unroll
    for (int it = 0; it < 8; ++it) {
      f32x4 p;
#pragma unroll
      for (int j = 0; j < 4; ++j) {
        float z = (x[it][j] - m[it][j]) * iv[it][j];
        // logp = -0.5 z^2 - log(sigma) - 0.5 log(2pi); log(sigma) = -log(inv)
        p[j] = fmaf(-0.5f * z, z, __logf(iv[it][j]) - 0.5f * LOG2PI_F);
      }
      float* o4 = ob + it * 1024;
      __builtin_nontemporal_store(p[0], o4 + 0);
      __builtin_nontemporal_store(p[1], o4 + 1);
      __builtin_nontemporal_store(p[2], o4 + 2);
      __builtin_nontemporal_store(p[3], o4 + 3);
      acc += (p[0] + p[1]) + (p[2] + p[3]);
    }
  }

#pragma unroll
  for (int off = 32; off; off >>= 1) acc += __shfl_down(acc, off, 64);
  __shared__ float s_w[4];
  int lane = threadIdx.x & 63, w = threadIdx.x >> 6;
  if (lane == 0) s_w[w] = acc;
  __syncthreads();
  if (threadIdx.x == 0)
    partial[blockIdx.x] = (s_w[0] + s_w[1]) + (s_w[2] + s_w[3]);
}

// ---------------- Kernel 3: final reduction (deterministic, double) ----------------
__global__ __launch_bounds__(256) void reduce_kernel(
    const float* __restrict__ partial, int n, float* __restrict__ out0) {
  double acc = 0.0;
  for (int i = threadIdx.x; i < n; i += 256) acc += (double)partial[i];
#pragma unroll
  for (int off = 32; off; off >>= 1) acc += __shfl_down(acc, off, 64);
  __shared__ double s_w[4];
  int lane = threadIdx.x & 63, w = threadIdx.x >> 6;
  if (lane == 0) s_w[w] = acc;
  __syncthreads();
  if (threadIdx.x == 0) out0[0] = (float)((s_w[0] + s_w[1]) + (s_w[2] + s_w[3]));
}

extern "C" void kernel_launch(void* const* d_in, const int* in_sizes, int n_in,
                              void* d_out, int out_size, void* d_ws, size_t ws_size,
                              hipStream_t stream) {
  const float* cp  = (const float*)d_in[0];   // (32,128)
  const float* Zmu = (const float*)d_in[1];   // (128,8192)
  const float* Zs  = (const float*)d_in[2];   // (128,8192)
  const float* X   = (const float*)d_in[3];   // (8192,8192)
  const int*   day = (const int*)d_in[4];     // (8192,)
  float* out = (float*)d_out;                 // [0]=sum, [1..]=logp flat
  float* ws  = (float*)d_ws;

  const int TBL = N_STATES * N_GENES;
  float* muT     = ws;
  float* invT    = ws + TBL;
  float* partial = ws + 2 * TBL;

  dim3 g1(N_GENES / 1024, N_STATES);          // 8 x 32 = 256 blocks
  precompute_kernel<<<g1, 256, 0, stream>>>(cp, Zmu, Zs, muT, invT);

  const int NBLK = N_SAMPLES / 4;             // 2048 blocks, 4 rows each
  main_kernel<<<NBLK, 256, 0, stream>>>(X, day, muT, invT, out, partial);
  reduce_kernel<<<1, 256, 0, stream>>>(partial, NBLK, out);
}